// Round 3
// baseline (25942.593 us; speedup 1.0000x reference)
//
#include <hip/hip_runtime.h>

constexpr int B_ = 64, I_ = 256, H_ = 512, T_ = 512;
constexpr int BH_ = B_ * H_;
constexpr int GBLK = 32;    // blocks per barrier group (= one b-tile's 32 j-blocks)

// d_ws layout: [0, 256KB) h ping-pong | [256KB, 258KB) barrier counters | [512KB, +33.5MB) xT
constexpr size_t WS_CNT_OFF = 262144;
constexpr size_t WS_XT_OFF  = 524288;

__device__ __forceinline__ float sigm(float v) { return 1.0f / (1.0f + __expf(-v)); }

// x (B,I,T) -> xT (T,B,I), one-time, coalesced both sides via LDS tile
__global__ __launch_bounds__(256)
void transpose_x(const float* __restrict__ x, float* __restrict__ xT)
{
    __shared__ float tile[32][33];
    const int b  = blockIdx.z;
    const int i0 = blockIdx.y << 5;
    const int t0 = blockIdx.x << 5;
    const int lt = threadIdx.x;      // 0..31
    const int li = threadIdx.y;      // 0..7
#pragma unroll
    for (int r = 0; r < 4; ++r) {
        int i = li + (r << 3);
        tile[i][lt] = x[((size_t)b * I_ + (i0 + i)) * T_ + (t0 + lt)];
    }
    __syncthreads();
#pragma unroll
    for (int r = 0; r < 4; ++r) {
        int tt = li + (r << 3);
        xT[((size_t)(t0 + tt) * B_ + b) * I_ + (i0 + lt)] = tile[lt][tt];
    }
}

__global__ __launch_bounds__(512, 1)
void lstm_fused(const float* __restrict__ x,
                const float* __restrict__ xT,     // nullptr -> strided fallback
                const float* __restrict__ Wih,
                const float* __restrict__ Whh,
                const float* __restrict__ bih,
                const float* __restrict__ bhh,
                const float* __restrict__ h0,
                const float* __restrict__ c0,
                float* __restrict__ out,
                float* __restrict__ hbuf,
                unsigned* __restrict__ cnt)
{
    // pad rows: stride % 32 banks == 4 -> 8 b-rows land on disjoint bank quads
    __shared__ float xs[8][I_ + 4];
    __shared__ float hs[8][H_ + 4];
    __shared__ float red[4][4][129];

    const int tid  = threadIdx.x;
    const int wave = tid >> 6;
    const int lane = tid & 63;
    const int kq   = wave >> 1;                 // k-quarter 0..3 (uniform per wave)
    const int p    = ((wave & 1) << 6) | lane;  // pair index 0..127
    const int bl   = p & 7;                     // local batch 0..7
    const int jl   = p >> 3;                    // local j 0..15

    const int blk = blockIdx.x;
    const int bt  = blk >> 5;                                // b-tile 0..7 = barrier group
    const int jt  = ((blk & 7) << 2) | ((blk >> 3) & 3);     // j-tile, XCD-clustered weights
    const int b0  = bt << 3;
    const int b   = b0 + bl;
    const int j   = (jt << 4) + jl;

    unsigned* gcnt = cnt + (size_t)bt * 64;     // 256B-separated counter per group

    float bias[4];
#pragma unroll
    for (int g = 0; g < 4; ++g) bias[g] = bih[g * H_ + j] + bhh[g * H_ + j];

    float c = c0[b * H_ + j];                   // cell state in-register all 512 steps

    // K partition over float4 units: x 64 + h 128 = 192; 48 per quarter
    const int nxA[4] = {48, 16, 0, 0};
    const int xoA[4] = {0, 48, 0, 0};
    const int nhA[4] = {0, 32, 48, 48};
    const int hoA[4] = {0, 0, 32, 80};
    const int nx = nxA[kq], xo = xoA[kq], nh = nhA[kq], ho = hoA[kq];

    const float4* wX[4];
    const float4* wH[4];
#pragma unroll
    for (int g = 0; g < 4; ++g) {
        wX[g] = (const float4*)(Wih + (size_t)(g * H_ + j) * I_) + xo;
        wH[g] = (const float4*)(Whh + (size_t)(g * H_ + j) * H_) + ho;
    }
    const float4* actX = (const float4*)(&xs[bl][0]) + xo;
    const float4* actH = (const float4*)(&hs[bl][0]) + ho;

    float* enc = out + BH_;

    for (int t = 0; t < T_; ++t) {
        // ---- stage x(:,:,t) for our 8 batches ----
        if (xT) {
            // (T,B,I): 8KB contiguous slab, 1 float4 per thread, fully coalesced
            float4 v = ((const float4*)(xT + ((size_t)t * B_ + b0) * I_))[tid];
            int bb = tid >> 6, k4 = tid & 63;
            *(float4*)(&xs[bb][k4 << 2]) = v;
        } else {
#pragma unroll
            for (int r = 0; r < 4; ++r) {
                int flat = tid + (r << 9);
                int bb = flat >> 8, ii = flat & 255;
                xs[bb][ii] = x[(size_t)((b0 + bb) * I_ + ii) * T_ + t];
            }
        }
        // ---- stage h (coalesced float4) ----
        const float* hsrc = t ? (hbuf + ((t - 1) & 1) * BH_) : h0;
#pragma unroll
        for (int r = 0; r < 2; ++r) {
            int flat = tid + (r << 9);
            int bb = flat >> 7, k4 = flat & 127;
            float4 v = ((const float4*)(hsrc + (size_t)(b0 + bb) * H_))[k4];
            *(float4*)(&hs[bb][k4 << 2]) = v;
        }
        __syncthreads();

        // ---- 4 gate dot-products over this thread's K slice ----
        float4 a0 = make_float4(0.f,0.f,0.f,0.f), a1 = a0, a2 = a0, a3 = a0;
#pragma unroll 4
        for (int k = 0; k < nx; ++k) {
            float4 a = actX[k];
            float4 w0 = wX[0][k], w1 = wX[1][k], w2 = wX[2][k], w3 = wX[3][k];
            a0.x += a.x*w0.x; a0.y += a.y*w0.y; a0.z += a.z*w0.z; a0.w += a.w*w0.w;
            a1.x += a.x*w1.x; a1.y += a.y*w1.y; a1.z += a.z*w1.z; a1.w += a.w*w1.w;
            a2.x += a.x*w2.x; a2.y += a.y*w2.y; a2.z += a.z*w2.z; a2.w += a.w*w2.w;
            a3.x += a.x*w3.x; a3.y += a.y*w3.y; a3.z += a.z*w3.z; a3.w += a.w*w3.w;
        }
#pragma unroll 4
        for (int k = 0; k < nh; ++k) {
            float4 a = actH[k];
            float4 w0 = wH[0][k], w1 = wH[1][k], w2 = wH[2][k], w3 = wH[3][k];
            a0.x += a.x*w0.x; a0.y += a.y*w0.y; a0.z += a.z*w0.z; a0.w += a.w*w0.w;
            a1.x += a.x*w1.x; a1.y += a.y*w1.y; a1.z += a.z*w1.z; a1.w += a.w*w1.w;
            a2.x += a.x*w2.x; a2.y += a.y*w2.y; a2.z += a.z*w2.z; a2.w += a.w*w2.w;
            a3.x += a.x*w3.x; a3.y += a.y*w3.y; a3.z += a.z*w3.z; a3.w += a.w*w3.w;
        }

        red[kq][0][p] = a0.x + a0.y + a0.z + a0.w;
        red[kq][1][p] = a1.x + a1.y + a1.z + a1.w;
        red[kq][2][p] = a2.x + a2.y + a2.z + a2.w;
        red[kq][3][p] = a3.x + a3.y + a3.z + a3.w;
        __syncthreads();

        // ---- waves 0-1 finalize: reduce quarters, gate math, state update, writes ----
        if (wave < 2) {
            float g0 = red[0][0][p] + red[1][0][p] + red[2][0][p] + red[3][0][p] + bias[0];
            float g1 = red[0][1][p] + red[1][1][p] + red[2][1][p] + red[3][1][p] + bias[1];
            float g2 = red[0][2][p] + red[1][2][p] + red[2][2][p] + red[3][2][p] + bias[2];
            float g3 = red[0][3][p] + red[1][3][p] + red[2][3][p] + red[3][3][p] + bias[3];
            float ig = sigm(g0);
            float fg = sigm(g1);
            float gg = tanhf(g2);
            float og = sigm(g3);
            c = fg * c + ig * gg;
            float hv = og * tanhf(c);
            hbuf[(t & 1) * BH_ + b * H_ + j] = hv;
            enc[(size_t)(b * H_ + j) * T_ + t] = hv;
            if (t == T_ - 1) out[b * H_ + j] = hv;
        }

        // ---- 32-block group barrier (monotonic counter, agent-scope) ----
        if (t != T_ - 1) {
            __syncthreads();                       // all writes of this block issued
            if (tid == 0) {
                __threadfence();                   // release: h visible device-wide
                atomicAdd(gcnt, 1u);
                const unsigned target = (unsigned)(GBLK * (t + 1));
                while (__hip_atomic_load(gcnt, __ATOMIC_RELAXED,
                                         __HIP_MEMORY_SCOPE_AGENT) < target)
                    __builtin_amdgcn_s_sleep(1);
            }
            __syncthreads();
            __threadfence();                       // acquire: invalidate stale h lines
        }
    }
}

extern "C" void kernel_launch(void* const* d_in, const int* in_sizes, int n_in,
                              void* d_out, int out_size, void* d_ws, size_t ws_size,
                              hipStream_t stream)
{
    (void)in_sizes; (void)n_in; (void)out_size;
    const float* x   = (const float*)d_in[0];
    const float* Wih = (const float*)d_in[1];
    const float* Whh = (const float*)d_in[2];
    const float* bih = (const float*)d_in[3];
    const float* bhh = (const float*)d_in[4];
    const float* h0  = (const float*)d_in[5];
    const float* c0  = (const float*)d_in[6];
    float* out  = (float*)d_out;
    float* hbuf = (float*)d_ws;
    unsigned* cnt = (unsigned*)((char*)d_ws + WS_CNT_OFF);

    const size_t xt_bytes = (size_t)T_ * B_ * I_ * sizeof(float);
    float* xT = nullptr;
    if (ws_size >= WS_XT_OFF + xt_bytes)
        xT = (float*)((char*)d_ws + WS_XT_OFF);

    // zero barrier counters every launch (deterministic across graph replays)
    hipMemsetAsync((char*)d_ws + WS_CNT_OFF, 0, 2048, stream);
    if (xT)
        transpose_x<<<dim3(T_ / 32, I_ / 32, B_), dim3(32, 8), 0, stream>>>(x, xT);

    void* args[] = { (void*)&x, (void*)&xT, (void*)&Wih, (void*)&Whh, (void*)&bih,
                     (void*)&bhh, (void*)&h0, (void*)&c0, (void*)&out,
                     (void*)&hbuf, (void*)&cnt };
    hipLaunchCooperativeKernel((void*)lstm_fused, dim3(256), dim3(512), args, 0, stream);
}

// Round 4
// 7896.809 us; speedup vs baseline: 3.2852x; 3.2852x over previous
//
#include <hip/hip_runtime.h>

constexpr int B_ = 64, I_ = 256, H_ = 512, T_ = 512;
constexpr int BH_ = B_ * H_;
constexpr int GBLK = 32;    // blocks per barrier group (= one b-tile's 32 j-blocks)

// d_ws layout: [0, 256KB) h ping-pong | [256KB, 258KB) barrier counters | [512KB, +33.5MB) xT
constexpr size_t WS_CNT_OFF = 262144;
constexpr size_t WS_XT_OFF  = 524288;

__device__ __forceinline__ float sigm(float v) { return 1.0f / (1.0f + __expf(-v)); }

// x (B,I,T) -> xT (T,B,I), one-time, coalesced both sides via LDS tile
__global__ __launch_bounds__(256)
void transpose_x(const float* __restrict__ x, float* __restrict__ xT)
{
    __shared__ float tile[32][33];
    const int b  = blockIdx.z;
    const int i0 = blockIdx.y << 5;
    const int t0 = blockIdx.x << 5;
    const int lt = threadIdx.x;      // 0..31
    const int li = threadIdx.y;      // 0..7
#pragma unroll
    for (int r = 0; r < 4; ++r) {
        int i = li + (r << 3);
        tile[i][lt] = x[((size_t)b * I_ + (i0 + i)) * T_ + (t0 + lt)];
    }
    __syncthreads();
#pragma unroll
    for (int r = 0; r < 4; ++r) {
        int tt = li + (r << 3);
        xT[((size_t)(t0 + tt) * B_ + b) * I_ + (i0 + lt)] = tile[lt][tt];
    }
}

__global__ __launch_bounds__(512, 1)
void lstm_fused(const float* __restrict__ x,
                const float* __restrict__ xT,     // nullptr -> strided fallback
                const float* __restrict__ Wih,
                const float* __restrict__ Whh,
                const float* __restrict__ bih,
                const float* __restrict__ bhh,
                const float* __restrict__ h0,
                const float* __restrict__ c0,
                float* __restrict__ out,
                float* __restrict__ hbuf,
                unsigned* __restrict__ cnt)
{
    // pad rows: stride % 32 banks == 4 -> 8 b-rows land on disjoint bank quads
    __shared__ float xs[8][I_ + 4];
    __shared__ float hs[8][H_ + 4];
    __shared__ float red[4][4][129];

    const int tid  = threadIdx.x;
    const int wave = tid >> 6;
    const int lane = tid & 63;
    const int kq   = wave >> 1;                 // k-quarter 0..3 (uniform per wave)
    const int p    = ((wave & 1) << 6) | lane;  // pair index 0..127
    const int bl   = p & 7;                     // local batch 0..7
    const int jl   = p >> 3;                    // local j 0..15

    const int blk = blockIdx.x;
    const int bt  = blk >> 5;                                // b-tile 0..7 = barrier group
    const int jt  = ((blk & 7) << 2) | ((blk >> 3) & 3);     // j-tile, XCD-clustered weights
    const int b0  = bt << 3;
    const int b   = b0 + bl;
    const int j   = (jt << 4) + jl;

    unsigned* gcnt = cnt + (size_t)bt * 64;     // 256B-separated counter per group

    float bias[4];
#pragma unroll
    for (int g = 0; g < 4; ++g) bias[g] = bih[g * H_ + j] + bhh[g * H_ + j];

    float c = c0[b * H_ + j];                   // cell state in-register all 512 steps

    // K partition over float4 units: x 64 + h 128 = 192; 48 per quarter
    const int nxA[4] = {48, 16, 0, 0};
    const int xoA[4] = {0, 48, 0, 0};
    const int nhA[4] = {0, 32, 48, 48};
    const int hoA[4] = {0, 0, 32, 80};
    const int nx = nxA[kq], xo = xoA[kq], nh = nhA[kq], ho = hoA[kq];

    const float4* wX[4];
    const float4* wH[4];
#pragma unroll
    for (int g = 0; g < 4; ++g) {
        wX[g] = (const float4*)(Wih + (size_t)(g * H_ + j) * I_) + xo;
        wH[g] = (const float4*)(Whh + (size_t)(g * H_ + j) * H_) + ho;
    }
    const float4* actX = (const float4*)(&xs[bl][0]) + xo;
    const float4* actH = (const float4*)(&hs[bl][0]) + ho;

    float* enc = out + BH_;

    for (int t = 0; t < T_; ++t) {
        // ---- stage x(:,:,t) for our 8 batches (read-only: normal cached loads) ----
        if (xT) {
            float4 v = ((const float4*)(xT + ((size_t)t * B_ + b0) * I_))[tid];
            int bb = tid >> 6, k4 = tid & 63;
            *(float4*)(&xs[bb][k4 << 2]) = v;
        } else {
#pragma unroll
            for (int r = 0; r < 4; ++r) {
                int flat = tid + (r << 9);
                int bb = flat >> 8, ii = flat & 255;
                xs[bb][ii] = x[(size_t)((b0 + bb) * I_ + ii) * T_ + t];
            }
        }
        // ---- stage h: system-scope relaxed loads (sc0 sc1 -> bypass L1/L2, read
        //      the coherence point; no acquire fence needed, no stale lines possible)
        {
            const unsigned* hsrcu = (const unsigned*)(t ? (hbuf + ((t - 1) & 1) * BH_) : h0)
                                    + (size_t)b0 * H_;
#pragma unroll
            for (int r = 0; r < 8; ++r) {
                unsigned u = __hip_atomic_load(hsrcu + (size_t)r * H_ + tid,
                                               __ATOMIC_RELAXED, __HIP_MEMORY_SCOPE_SYSTEM);
                hs[r][tid] = __uint_as_float(u);
            }
        }
        __syncthreads();

        // ---- 4 gate dot-products over this thread's K slice ----
        float4 a0 = make_float4(0.f,0.f,0.f,0.f), a1 = a0, a2 = a0, a3 = a0;
#pragma unroll 4
        for (int k = 0; k < nx; ++k) {
            float4 a = actX[k];
            float4 w0 = wX[0][k], w1 = wX[1][k], w2 = wX[2][k], w3 = wX[3][k];
            a0.x += a.x*w0.x; a0.y += a.y*w0.y; a0.z += a.z*w0.z; a0.w += a.w*w0.w;
            a1.x += a.x*w1.x; a1.y += a.y*w1.y; a1.z += a.z*w1.z; a1.w += a.w*w1.w;
            a2.x += a.x*w2.x; a2.y += a.y*w2.y; a2.z += a.z*w2.z; a2.w += a.w*w2.w;
            a3.x += a.x*w3.x; a3.y += a.y*w3.y; a3.z += a.z*w3.z; a3.w += a.w*w3.w;
        }
#pragma unroll 4
        for (int k = 0; k < nh; ++k) {
            float4 a = actH[k];
            float4 w0 = wH[0][k], w1 = wH[1][k], w2 = wH[2][k], w3 = wH[3][k];
            a0.x += a.x*w0.x; a0.y += a.y*w0.y; a0.z += a.z*w0.z; a0.w += a.w*w0.w;
            a1.x += a.x*w1.x; a1.y += a.y*w1.y; a1.z += a.z*w1.z; a1.w += a.w*w1.w;
            a2.x += a.x*w2.x; a2.y += a.y*w2.y; a2.z += a.z*w2.z; a2.w += a.w*w2.w;
            a3.x += a.x*w3.x; a3.y += a.y*w3.y; a3.z += a.z*w3.z; a3.w += a.w*w3.w;
        }

        red[kq][0][p] = a0.x + a0.y + a0.z + a0.w;
        red[kq][1][p] = a1.x + a1.y + a1.z + a1.w;
        red[kq][2][p] = a2.x + a2.y + a2.z + a2.w;
        red[kq][3][p] = a3.x + a3.y + a3.z + a3.w;
        __syncthreads();

        // ---- waves 0-1 finalize: reduce quarters, gate math, state update, writes ----
        if (wave < 2) {
            float g0 = red[0][0][p] + red[1][0][p] + red[2][0][p] + red[3][0][p] + bias[0];
            float g1 = red[0][1][p] + red[1][1][p] + red[2][1][p] + red[3][1][p] + bias[1];
            float g2 = red[0][2][p] + red[1][2][p] + red[2][2][p] + red[3][2][p] + bias[2];
            float g3 = red[0][3][p] + red[1][3][p] + red[2][3][p] + red[3][3][p] + bias[3];
            float ig = sigm(g0);
            float fg = sigm(g1);
            float gg = tanhf(g2);
            float og = sigm(g3);
            c = fg * c + ig * gg;
            float hv = og * tanhf(c);
            // publish h through the coherence point: write-through store, no fence
            __hip_atomic_store((unsigned*)(hbuf + (t & 1) * BH_) + (size_t)b * H_ + j,
                               __float_as_uint(hv),
                               __ATOMIC_RELAXED, __HIP_MEMORY_SCOPE_SYSTEM);
            enc[(size_t)(b * H_ + j) * T_ + t] = hv;        // plain cached store (read at kernel end only)
            if (t == T_ - 1) out[b * H_ + j] = hv;
        }

        // ---- 32-block group barrier, FENCE-FREE ----
        if (t != T_ - 1) {
            // h stores are sc0 sc1 write-through: once vmcnt retires they are at the
            // coherence point -> a bare waitcnt replaces the L2-flush release fence.
            asm volatile("s_waitcnt vmcnt(0)" ::: "memory");
            __syncthreads();                      // finalize-wave stores retired before signal
            if (tid == 0) {
                __hip_atomic_fetch_add(gcnt, 1u, __ATOMIC_RELAXED, __HIP_MEMORY_SCOPE_SYSTEM);
                const unsigned target = (unsigned)(GBLK * (t + 1));
                while (__hip_atomic_load(gcnt, __ATOMIC_RELAXED,
                                         __HIP_MEMORY_SCOPE_SYSTEM) < target)
                    __builtin_amdgcn_s_sleep(1);
            }
            __syncthreads();                      // no acquire fence: h reads bypass caches
        }
    }
}

extern "C" void kernel_launch(void* const* d_in, const int* in_sizes, int n_in,
                              void* d_out, int out_size, void* d_ws, size_t ws_size,
                              hipStream_t stream)
{
    (void)in_sizes; (void)n_in; (void)out_size;
    const float* x   = (const float*)d_in[0];
    const float* Wih = (const float*)d_in[1];
    const float* Whh = (const float*)d_in[2];
    const float* bih = (const float*)d_in[3];
    const float* bhh = (const float*)d_in[4];
    const float* h0  = (const float*)d_in[5];
    const float* c0  = (const float*)d_in[6];
    float* out  = (float*)d_out;
    float* hbuf = (float*)d_ws;
    unsigned* cnt = (unsigned*)((char*)d_ws + WS_CNT_OFF);

    const size_t xt_bytes = (size_t)T_ * B_ * I_ * sizeof(float);
    float* xT = nullptr;
    if (ws_size >= WS_XT_OFF + xt_bytes)
        xT = (float*)((char*)d_ws + WS_XT_OFF);

    // zero barrier counters every launch (deterministic across graph replays)
    hipMemsetAsync((char*)d_ws + WS_CNT_OFF, 0, 2048, stream);
    if (xT)
        transpose_x<<<dim3(T_ / 32, I_ / 32, B_), dim3(32, 8), 0, stream>>>(x, xT);

    void* args[] = { (void*)&x, (void*)&xT, (void*)&Wih, (void*)&Whh, (void*)&bih,
                     (void*)&bhh, (void*)&h0, (void*)&c0, (void*)&out,
                     (void*)&hbuf, (void*)&cnt };
    hipLaunchCooperativeKernel((void*)lstm_fused, dim3(256), dim3(512), args, 0, stream);
}

// Round 5
// 7149.357 us; speedup vs baseline: 3.6287x; 1.1045x over previous
//
#include <hip/hip_runtime.h>

constexpr int B_ = 64, I_ = 256, H_ = 512, T_ = 512;
constexpr int BH_ = B_ * H_;
constexpr int GBLK = 32;    // blocks per barrier group (= one b-tile's 32 j-blocks)

// d_ws layout: [0, 256KB) h ping-pong | [256KB, 512KB) barrier counters | [512KB, +33.5MB) xT
constexpr size_t WS_CNT_OFF = 262144;
constexpr size_t WS_XT_OFF  = 524288;

typedef float f32x4 __attribute__((ext_vector_type(4)));

__device__ __forceinline__ float sigm(float v) { return 1.0f / (1.0f + __expf(-v)); }

// x (B,I,T) -> xT (T,B,I), one-time, coalesced both sides via LDS tile
__global__ __launch_bounds__(256)
void transpose_x(const float* __restrict__ x, float* __restrict__ xT)
{
    __shared__ float tile[32][33];
    const int b  = blockIdx.z;
    const int i0 = blockIdx.y << 5;
    const int t0 = blockIdx.x << 5;
    const int lt = threadIdx.x;      // 0..31
    const int li = threadIdx.y;      // 0..7
#pragma unroll
    for (int r = 0; r < 4; ++r) {
        int i = li + (r << 3);
        tile[i][lt] = x[((size_t)b * I_ + (i0 + i)) * T_ + (t0 + lt)];
    }
    __syncthreads();
#pragma unroll
    for (int r = 0; r < 4; ++r) {
        int tt = li + (r << 3);
        xT[((size_t)(t0 + tt) * B_ + b) * I_ + (i0 + lt)] = tile[lt][tt];
    }
}

__global__ __launch_bounds__(512, 1)
void lstm_fused(const float* __restrict__ x,
                const float* __restrict__ xT,     // nullptr -> strided fallback
                const float* __restrict__ Wih,
                const float* __restrict__ Whh,
                const float* __restrict__ bih,
                const float* __restrict__ bhh,
                const float* __restrict__ h0,
                const float* __restrict__ c0,
                float* __restrict__ out,
                float* __restrict__ hbuf,
                unsigned* __restrict__ cnt)
{
    __shared__ float xs[8][I_ + 4];
    __shared__ float hs[8][H_ + 4];
    __shared__ float red[4][4][129];
    __shared__ float hpub[8][16];     // this block's h contribution (8 b x 16 j)

    const int tid  = threadIdx.x;
    const int wave = tid >> 6;
    const int lane = tid & 63;
    const int kq   = wave >> 1;                 // k-quarter 0..3 (uniform per wave)
    const int p    = ((wave & 1) << 6) | lane;  // pair index 0..127
    const int bl   = p & 7;                     // local batch 0..7
    const int jl   = p >> 3;                    // local j 0..15

    const int blk = blockIdx.x;
    const int bt  = blk >> 5;                                // b-tile 0..7 = barrier group
    const int jt  = ((blk & 7) << 2) | ((blk >> 3) & 3);     // j-tile, XCD-clustered weights
    const int b0  = bt << 3;
    const int b   = b0 + bl;
    const int j   = (jt << 4) + jl;

    unsigned* gcnt = cnt + (size_t)bt * 1024;   // 4KB-separated counter per group

    float bias[4];
#pragma unroll
    for (int g = 0; g < 4; ++g) bias[g] = bih[g * H_ + j] + bhh[g * H_ + j];

    float c = c0[b * H_ + j];                   // cell state in-register all 512 steps

    // K partition over float4 units: x 64 + h 128 = 192; 48 per quarter
    const int nxA[4] = {48, 16, 0, 0};
    const int xoA[4] = {0, 48, 0, 0};
    const int nhA[4] = {0, 32, 48, 48};
    const int hoA[4] = {0, 0, 32, 80};
    const int nx = nxA[kq], xo = xoA[kq], nh = nhA[kq], ho = hoA[kq];

    const float4* wX[4];
    const float4* wH[4];
#pragma unroll
    for (int g = 0; g < 4; ++g) {
        wX[g] = (const float4*)(Wih + (size_t)(g * H_ + j) * I_) + xo;
        wH[g] = (const float4*)(Whh + (size_t)(g * H_ + j) * H_) + ho;
    }
    const float4* actX = (const float4*)(&xs[bl][0]) + xo;
    const float4* actH = (const float4*)(&hs[bl][0]) + ho;

    float* enc = out + BH_;

    // prefetch x slab for t=0 into registers (cached load; compiler tracks the dep)
    float4 xv;
    if (xT) xv = ((const float4*)(xT + (size_t)0 * B_ * I_ + (size_t)b0 * I_))[tid];

    for (int t = 0; t < T_; ++t) {
        // ---- commit prefetched x to LDS ----
        if (xT) {
            int bb = tid >> 6, k4 = tid & 63;
            *(float4*)(&xs[bb][k4 << 2]) = xv;
        } else {
#pragma unroll
            for (int r = 0; r < 4; ++r) {
                int flat = tid + (r << 9);
                int bb = flat >> 8, ii = flat & 255;
                xs[bb][ii] = x[(size_t)((b0 + bb) * I_ + ii) * T_ + t];
            }
        }
        // ---- stage h: uncached (sc0 sc1) dwordx4 reads of the coherence point ----
        {
            const float* hsrc = t ? (hbuf + ((t - 1) & 1) * BH_) : h0;
            const int f0 = tid, f1 = tid + 512;
            const float* a0 = hsrc + ((size_t)(b0 + (f0 >> 7)) << 9) + ((f0 & 127) << 2);
            const float* a1 = hsrc + ((size_t)(b0 + (f1 >> 7)) << 9) + ((f1 & 127) << 2);
            f32x4 v0, v1;
            asm volatile("global_load_dwordx4 %0, %2, off sc0 sc1\n\t"
                         "global_load_dwordx4 %1, %3, off sc0 sc1\n\t"
                         "s_waitcnt vmcnt(0)"
                         : "=&v"(v0), "=&v"(v1)
                         : "v"(a0), "v"(a1)
                         : "memory");
            __builtin_amdgcn_sched_barrier(0);
            *(f32x4*)(&hs[f0 >> 7][(f0 & 127) << 2]) = v0;
            *(f32x4*)(&hs[f1 >> 7][(f1 & 127) << 2]) = v1;
        }
        __syncthreads();

        // ---- 4 gate dot-products over this thread's K slice ----
        float4 a0 = make_float4(0.f,0.f,0.f,0.f), a1 = a0, a2 = a0, a3 = a0;
#pragma unroll 4
        for (int k = 0; k < nx; ++k) {
            float4 a = actX[k];
            float4 w0 = wX[0][k], w1 = wX[1][k], w2 = wX[2][k], w3 = wX[3][k];
            a0.x += a.x*w0.x; a0.y += a.y*w0.y; a0.z += a.z*w0.z; a0.w += a.w*w0.w;
            a1.x += a.x*w1.x; a1.y += a.y*w1.y; a1.z += a.z*w1.z; a1.w += a.w*w1.w;
            a2.x += a.x*w2.x; a2.y += a.y*w2.y; a2.z += a.z*w2.z; a2.w += a.w*w2.w;
            a3.x += a.x*w3.x; a3.y += a.y*w3.y; a3.z += a.z*w3.z; a3.w += a.w*w3.w;
        }
#pragma unroll 4
        for (int k = 0; k < nh; ++k) {
            float4 a = actH[k];
            float4 w0 = wH[0][k], w1 = wH[1][k], w2 = wH[2][k], w3 = wH[3][k];
            a0.x += a.x*w0.x; a0.y += a.y*w0.y; a0.z += a.z*w0.z; a0.w += a.w*w0.w;
            a1.x += a.x*w1.x; a1.y += a.y*w1.y; a1.z += a.z*w1.z; a1.w += a.w*w1.w;
            a2.x += a.x*w2.x; a2.y += a.y*w2.y; a2.z += a.z*w2.z; a2.w += a.w*w2.w;
            a3.x += a.x*w3.x; a3.y += a.y*w3.y; a3.z += a.z*w3.z; a3.w += a.w*w3.w;
        }

        red[kq][0][p] = a0.x + a0.y + a0.z + a0.w;
        red[kq][1][p] = a1.x + a1.y + a1.z + a1.w;
        red[kq][2][p] = a2.x + a2.y + a2.z + a2.w;
        red[kq][3][p] = a3.x + a3.y + a3.z + a3.w;
        __syncthreads();

        // ---- waves 0-1 finalize: reduce quarters, gate math, state update ----
        if (wave < 2) {
            float g0 = red[0][0][p] + red[1][0][p] + red[2][0][p] + red[3][0][p] + bias[0];
            float g1 = red[0][1][p] + red[1][1][p] + red[2][1][p] + red[3][1][p] + bias[1];
            float g2 = red[0][2][p] + red[1][2][p] + red[2][2][p] + red[3][2][p] + bias[2];
            float g3 = red[0][3][p] + red[1][3][p] + red[2][3][p] + red[3][3][p] + bias[3];
            float ig = sigm(g0);
            float fg = sigm(g1);
            float gg = tanhf(g2);
            float og = sigm(g3);
            c = fg * c + ig * gg;
            float hv = og * tanhf(c);
            hpub[bl][jl] = hv;                              // stage publish in LDS
            enc[(size_t)(b * H_ + j) * T_ + t] = hv;        // plain cached store
            if (t == T_ - 1) out[b * H_ + j] = hv;
        }
        __syncthreads();    // hpub ready; all xs/hs reads of step t done

        if (t != T_ - 1) {
            // prefetch next x while we publish + wait (latency hides under barrier)
            if (xT) xv = ((const float4*)(xT + (size_t)(t + 1) * B_ * I_ + (size_t)b0 * I_))[tid];

            // ---- publish h as 8 FULL 64B lines (write-through, no fence) ----
            if (tid < 32) {
                int bb = tid >> 2, q = tid & 3;
                f32x4 v = *(const f32x4*)(&hpub[bb][q << 2]);
                float* dst = hbuf + (size_t)(t & 1) * BH_
                           + ((size_t)(b0 + bb) << 9) + (jt << 4) + (q << 2);
                asm volatile("global_store_dwordx4 %0, %1, off sc0 sc1"
                             :: "v"(dst), "v"(v) : "memory");
            }
            if (wave == 0) {
                asm volatile("s_waitcnt vmcnt(0)" ::: "memory");  // publish at coherence point
                if (tid == 0) {
                    __hip_atomic_fetch_add(gcnt, 1u, __ATOMIC_RELAXED,
                                           __HIP_MEMORY_SCOPE_SYSTEM);
                    const unsigned target = (unsigned)(GBLK * (t + 1));
                    while (__hip_atomic_load(gcnt, __ATOMIC_RELAXED,
                                             __HIP_MEMORY_SCOPE_SYSTEM) < target)
                        __builtin_amdgcn_s_sleep(2);
                }
            }
            __syncthreads();    // group done: hbuf[t&1] fully published
        }
    }
}

extern "C" void kernel_launch(void* const* d_in, const int* in_sizes, int n_in,
                              void* d_out, int out_size, void* d_ws, size_t ws_size,
                              hipStream_t stream)
{
    (void)in_sizes; (void)n_in; (void)out_size;
    const float* x   = (const float*)d_in[0];
    const float* Wih = (const float*)d_in[1];
    const float* Whh = (const float*)d_in[2];
    const float* bih = (const float*)d_in[3];
    const float* bhh = (const float*)d_in[4];
    const float* h0  = (const float*)d_in[5];
    const float* c0  = (const float*)d_in[6];
    float* out  = (float*)d_out;
    float* hbuf = (float*)d_ws;
    unsigned* cnt = (unsigned*)((char*)d_ws + WS_CNT_OFF);

    const size_t xt_bytes = (size_t)T_ * B_ * I_ * sizeof(float);
    float* xT = nullptr;
    if (ws_size >= WS_XT_OFF + xt_bytes)
        xT = (float*)((char*)d_ws + WS_XT_OFF);

    // zero barrier counters every launch (deterministic across graph replays)
    hipMemsetAsync((char*)d_ws + WS_CNT_OFF, 0, 32768, stream);
    if (xT)
        transpose_x<<<dim3(T_ / 32, I_ / 32, B_), dim3(32, 8), 0, stream>>>(x, xT);

    void* args[] = { (void*)&x, (void*)&xT, (void*)&Wih, (void*)&Whh, (void*)&bih,
                     (void*)&bhh, (void*)&h0, (void*)&c0, (void*)&out,
                     (void*)&hbuf, (void*)&cnt };
    hipLaunchCooperativeKernel((void*)lstm_fused, dim3(256), dim3(512), args, 0, stream);
}

// Round 12
// 2431.413 us; speedup vs baseline: 10.6698x; 2.9404x over previous
//
#include <hip/hip_runtime.h>

constexpr int B_ = 64, I_ = 256, H_ = 512, T_ = 512;
constexpr int BH_ = B_ * H_;

// d_ws layout: [0,256KB) hbuf ping-pong | [256KB,+64KB) flags | [512KB,+33.5MB) xT
constexpr size_t WS_CNT_OFF = 262144;
constexpr size_t WS_XT_OFF  = 524288;
constexpr int C_FLAG = 512;     // word offset: [bt*64 + jt] per-block step flags

typedef float f32x4 __attribute__((ext_vector_type(4)));

__device__ __forceinline__ float sigm(float v) { return 1.0f / (1.0f + __expf(-v)); }

// system-scope (IF) uncached flag ops — the r5-proven visibility path
__device__ __forceinline__ unsigned flag_load(const unsigned* p) {
    unsigned v;
    asm volatile("global_load_dword %0, %1, off sc0 sc1\n\ts_waitcnt vmcnt(0)"
                 : "=v"(v) : "v"(p) : "memory");
    return v;
}
__device__ __forceinline__ void flag_store(unsigned* p, unsigned v) {
    asm volatile("global_store_dword %0, %1, off sc0 sc1" :: "v"(p), "v"(v) : "memory");
}

// x (B,I,T) -> xT (T,B,I), one-time
__global__ __launch_bounds__(256)
void transpose_x(const float* __restrict__ x, float* __restrict__ xT)
{
    __shared__ float tile[32][33];
    const int b  = blockIdx.z;
    const int i0 = blockIdx.y << 5;
    const int t0 = blockIdx.x << 5;
    const int lt = threadIdx.x;      // 0..31
    const int li = threadIdx.y;      // 0..7
#pragma unroll
    for (int r = 0; r < 4; ++r) {
        int i = li + (r << 3);
        tile[i][lt] = x[((size_t)b * I_ + (i0 + i)) * T_ + (t0 + lt)];
    }
    __syncthreads();
#pragma unroll
    for (int r = 0; r < 4; ++r) {
        int tt = li + (r << 3);
        xT[((size_t)(t0 + tt) * B_ + b) * I_ + (i0 + lt)] = tile[lt][tt];
    }
}

__global__ __launch_bounds__(512, 1)
void lstm_fused(const float* __restrict__ x,
                const float* __restrict__ xT,     // nullptr -> strided fallback
                const float* __restrict__ Wih,
                const float* __restrict__ Whh,
                const float* __restrict__ bih,
                const float* __restrict__ bhh,
                const float* __restrict__ h0,
                const float* __restrict__ c0,
                float* __restrict__ out,
                float* __restrict__ hbuf,
                unsigned* __restrict__ cnt)
{
    // smem arena: redA[16][133] f32x4 (34048 B, aliased by red2[4][133])
    // | act[8][772] f32 (24704 B) | hsh[128] f32 (512 B)
    __shared__ char smem[59264];
    f32x4* redA = (f32x4*)smem;
    f32x4* red2 = (f32x4*)smem;                       // alias (sync-protected)
    float* act  = (float*)(smem + 34048);
    float* hsh  = (float*)(smem + 34048 + 24704);

    const int tid  = threadIdx.x;
    const int wv   = tid >> 6;
    const int lane = tid & 63;
    const int jl   = lane & 15;           // j within block's 16
    const int sl   = wv * 4 + (lane >> 4);// k-slice 0..31

    // fixed team assignment: 8 teams (b-tiles) x 32 j-blocks
    const int blk = blockIdx.x;
    const int bt  = blk >> 5;
    const int jt  = blk & 31;
    const int b0  = bt << 3;
    const int j0  = jt << 4;
    unsigned* flags  = cnt + C_FLAG + bt * 64;   // team's 32 flag dwords
    unsigned* myflag = flags + jt;

    // ---- one-time: weight slices into registers ----
    // x-part: k in [sl*8, sl*8+8)  |  h-part: k-256 in [sl*16, sl*16+16)
    const int j = j0 + jl;
    float w_x[4][8];
    float w_h[4][16];
#pragma unroll
    for (int g = 0; g < 4; ++g) {
        const size_t row = (size_t)(g * H_ + j);
#pragma unroll
        for (int kk = 0; kk < 8; ++kk)  w_x[g][kk] = Wih[row * I_ + (sl << 3) + kk];
#pragma unroll
        for (int kk = 0; kk < 16; ++kk) w_h[g][kk] = Whh[row * H_ + (sl << 4) + kk];
    }

    // finalizer (tid<128) per-(b,j) state
    const int fb = b0 + (tid >> 4);
    const int fj = j0 + (tid & 15);
    float c = 0.f;
    f32x4 bias4 = {0.f, 0.f, 0.f, 0.f};
    if (tid < 128) {
        c = c0[(size_t)fb * H_ + fj];
#pragma unroll
        for (int g = 0; g < 4; ++g) bias4[g] = bih[g * H_ + fj] + bhh[g * H_ + fj];
    }

    float* enc = out + BH_;
    const int pr = tid & 127;    // reduce pair (bq = pr>>4, jl = pr&15)
    const int qq = tid >> 7;     // reduce quarter 0..3

    // prologue: prefetch x slab for t=0
    float4 xv;
    if (xT) xv = ((const float4*)(xT + (size_t)b0 * I_))[tid];

    for (int t = 0; t < T_; ++t) {
        // ---- (a) commit x(t) to act[.][0..256) ----
        if (xT) {
            *(float4*)(act + (tid >> 6) * 772 + ((tid & 63) << 2)) = xv;
        } else {
#pragma unroll
            for (int r = 0; r < 4; ++r) {
                int flat = tid + (r << 9), bb = flat >> 8, ii = flat & 255;
                act[bb * 772 + ii] = x[((size_t)(b0 + bb) * I_ + ii) * T_ + t];
            }
        }
        __syncthreads();                                   // act_x ready; prev reads done

        // ---- (c) FMA x-part (independent of h(t-1)) ----
        f32x4 r4[8];
#pragma unroll
        for (int bq = 0; bq < 8; ++bq) {
            const f32x4* ap = (const f32x4*)(act + bq * 772 + (sl << 3));
            float s0 = 0.f, s1 = 0.f, s2 = 0.f, s3 = 0.f;
#pragma unroll
            for (int q2 = 0; q2 < 2; ++q2) {
                f32x4 a = ap[q2];
#pragma unroll
                for (int e = 0; e < 4; ++e) {
                    const float av = a[e];
                    const int kk = q2 * 4 + e;
                    s0 += av * w_x[0][kk]; s1 += av * w_x[1][kk];
                    s2 += av * w_x[2][kk]; s3 += av * w_x[3][kk];
                }
            }
            r4[bq] = (f32x4){s0, s1, s2, s3};
        }

        // ---- (d) prefetch x(t+1) into registers (latency hides under the wait) ----
        if (xT && t + 1 < T_)
            xv = ((const float4*)(xT + (size_t)(t + 1) * B_ * I_ + (size_t)b0 * I_))[tid];

        // ---- (e) h(t-1) barrier: 32 lanes poll 32 flags (bounded) ----
        if (t > 0 && tid < 32) {
            const unsigned tgt = (unsigned)t;
            for (unsigned it = 0; it < (1u << 17); ++it) {
                unsigned v = flag_load(flags + tid);
                unsigned long long rdy = __ballot(v >= tgt);
                if ((rdy & 0xFFFFFFFFull) == 0xFFFFFFFFull) break;
                __builtin_amdgcn_s_sleep(1);
            }
        }
        __syncthreads();                                   // (f) flag observed by all

        // ---- (g) stage h(t-1) into act[.][256..768) ----
        {
            const int u0 = tid, u1 = tid + 512;
            if (t == 0) {
                float4 v0 = ((const float4*)(h0 + (size_t)(b0 + (u0 >> 7)) * H_))[u0 & 127];
                float4 v1 = ((const float4*)(h0 + (size_t)(b0 + (u1 >> 7)) * H_))[u1 & 127];
                *(float4*)(act + (u0 >> 7) * 772 + 256 + ((u0 & 127) << 2)) = v0;
                *(float4*)(act + (u1 >> 7) * 772 + 256 + ((u1 & 127) << 2)) = v1;
            } else {
                const float* hsrc = hbuf + (size_t)((t - 1) & 1) * BH_;
                const float* a0 = hsrc + (size_t)(b0 + (u0 >> 7)) * H_ + ((u0 & 127) << 2);
                const float* a1 = hsrc + (size_t)(b0 + (u1 >> 7)) * H_ + ((u1 & 127) << 2);
                f32x4 v0, v1;
                asm volatile("global_load_dwordx4 %0, %2, off sc0 sc1\n\t"
                             "global_load_dwordx4 %1, %3, off sc0 sc1\n\t"
                             "s_waitcnt vmcnt(0)"
                             : "=&v"(v0), "=&v"(v1) : "v"(a0), "v"(a1) : "memory");
                __builtin_amdgcn_sched_barrier(0);
                *(f32x4*)(act + (u0 >> 7) * 772 + 256 + ((u0 & 127) << 2)) = v0;
                *(f32x4*)(act + (u1 >> 7) * 772 + 256 + ((u1 & 127) << 2)) = v1;
            }
        }
        __syncthreads();                                   // (h) act_h ready

        // ---- (i) FMA h-part ----
#pragma unroll
        for (int bq = 0; bq < 8; ++bq) {
            const f32x4* ap = (const f32x4*)(act + bq * 772 + 256 + (sl << 4));
            float s0 = 0.f, s1 = 0.f, s2 = 0.f, s3 = 0.f;
#pragma unroll
            for (int q4 = 0; q4 < 4; ++q4) {
                f32x4 a = ap[q4];
#pragma unroll
                for (int e = 0; e < 4; ++e) {
                    const float av = a[e];
                    const int kk = q4 * 4 + e;
                    s0 += av * w_h[0][kk]; s1 += av * w_h[1][kk];
                    s2 += av * w_h[2][kk]; s3 += av * w_h[3][kk];
                }
            }
            r4[bq] += (f32x4){s0, s1, s2, s3};
        }

        // ---- (j) hierarchical reduce over 32 k-slices ----
        if (wv < 4) {
#pragma unroll
            for (int bq = 0; bq < 8; ++bq) redA[sl * 133 + bq * 16 + jl] = r4[bq];
        }
        __syncthreads();
        f32x4 acc = redA[(qq * 4 + 0) * 133 + pr] + redA[(qq * 4 + 1) * 133 + pr]
                  + redA[(qq * 4 + 2) * 133 + pr] + redA[(qq * 4 + 3) * 133 + pr];
        __syncthreads();
        if (wv >= 4) {
#pragma unroll
            for (int bq = 0; bq < 8; ++bq) redA[(sl - 16) * 133 + bq * 16 + jl] = r4[bq];
        }
        __syncthreads();
        acc += redA[(qq * 4 + 0) * 133 + pr] + redA[(qq * 4 + 1) * 133 + pr]
             + redA[(qq * 4 + 2) * 133 + pr] + redA[(qq * 4 + 3) * 133 + pr];
        __syncthreads();                       // protect redA reads before alias write
        red2[qq * 133 + pr] = acc;
        __syncthreads();

        // ---- (k) finalize: gates, state, enc ----
        if (tid < 128) {
            f32x4 G = red2[0 * 133 + tid] + red2[1 * 133 + tid]
                    + red2[2 * 133 + tid] + red2[3 * 133 + tid] + bias4;
            float ig = sigm(G[0]), fg = sigm(G[1]), gg = tanhf(G[2]), og = sigm(G[3]);
            c = fg * c + ig * gg;
            float hv = og * tanhf(c);
            hsh[tid] = hv;
            enc[((size_t)fb * H_ + fj) * T_ + t] = hv;          // plain cached store
            if (t == T_ - 1) out[(size_t)fb * H_ + fj] = hv;
        }

        // ---- (m) publish h (8 full 64B lines, sc0 sc1), drain, flag ----
        if (t != T_ - 1) {
            __syncthreads();                   // hsh ready
            if (tid < 32) {
                int bq = tid >> 2, q4 = tid & 3;
                f32x4 v = *(const f32x4*)(hsh + bq * 16 + q4 * 4);
                float* dst = hbuf + (size_t)(t & 1) * BH_
                           + (size_t)(b0 + bq) * H_ + j0 + q4 * 4;
                asm volatile("global_store_dwordx4 %0, %1, off sc0 sc1"
                             :: "v"(dst), "v"(v) : "memory");
            }
            if (wv == 0) {
                asm volatile("s_waitcnt vmcnt(0)" ::: "memory"); // wave0 publish at IF
                if (tid == 0) flag_store(myflag, (unsigned)(t + 1));
            }
        }
    }
}

extern "C" void kernel_launch(void* const* d_in, const int* in_sizes, int n_in,
                              void* d_out, int out_size, void* d_ws, size_t ws_size,
                              hipStream_t stream)
{
    (void)in_sizes; (void)n_in; (void)out_size;
    const float* x   = (const float*)d_in[0];
    const float* Wih = (const float*)d_in[1];
    const float* Whh = (const float*)d_in[2];
    const float* bih = (const float*)d_in[3];
    const float* bhh = (const float*)d_in[4];
    const float* h0  = (const float*)d_in[5];
    const float* c0  = (const float*)d_in[6];
    float* out  = (float*)d_out;
    float* hbuf = (float*)d_ws;
    unsigned* cnt = (unsigned*)((char*)d_ws + WS_CNT_OFF);

    const size_t xt_bytes = (size_t)T_ * B_ * I_ * sizeof(float);
    float* xT = nullptr;
    if (ws_size >= WS_XT_OFF + xt_bytes)
        xT = (float*)((char*)d_ws + WS_XT_OFF);

    // zero flags every launch (graph-replay deterministic)
    hipMemsetAsync((char*)d_ws + WS_CNT_OFF, 0, 65536, stream);
    if (xT)
        transpose_x<<<dim3(T_ / 32, I_ / 32, B_), dim3(32, 8), 0, stream>>>(x, xT);

    void* args[] = { (void*)&x, (void*)&xT, (void*)&Wih, (void*)&Whh, (void*)&bih,
                     (void*)&bhh, (void*)&h0, (void*)&c0, (void*)&out,
                     (void*)&hbuf, (void*)&cnt };
    hipLaunchCooperativeKernel((void*)lstm_fused, dim3(256), dim3(512), args, 0, stream);
}

// Round 13
// 2365.786 us; speedup vs baseline: 10.9657x; 1.0277x over previous
//
#include <hip/hip_runtime.h>

constexpr int B_ = 64, I_ = 256, H_ = 512, T_ = 512;
constexpr int BH_ = B_ * H_;

// d_ws layout: [0,256KB) hbuf ping-pong | [256KB,+64KB) flags | [512KB,+33.5MB) xT
constexpr size_t WS_CNT_OFF = 262144;
constexpr size_t WS_XT_OFF  = 524288;
constexpr int C_FLAG = 512;     // word offset: flag of (bt,jt) at [bt*512 + jt*16]

typedef float f32x4 __attribute__((ext_vector_type(4)));

__device__ __forceinline__ float sigm(float v) { return 1.0f / (1.0f + __expf(-v)); }

// system-scope (IF) uncached flag ops — the proven visibility path
__device__ __forceinline__ unsigned flag_load(const unsigned* p) {
    unsigned v;
    asm volatile("global_load_dword %0, %1, off sc0 sc1\n\ts_waitcnt vmcnt(0)"
                 : "=v"(v) : "v"(p) : "memory");
    return v;
}
__device__ __forceinline__ void flag_store(unsigned* p, unsigned v) {
    asm volatile("global_store_dword %0, %1, off sc0 sc1" :: "v"(p), "v"(v) : "memory");
}

// x (B,I,T) -> xT (T,B,I), one-time
__global__ __launch_bounds__(256)
void transpose_x(const float* __restrict__ x, float* __restrict__ xT)
{
    __shared__ float tile[32][33];
    const int b  = blockIdx.z;
    const int i0 = blockIdx.y << 5;
    const int t0 = blockIdx.x << 5;
    const int lt = threadIdx.x;      // 0..31
    const int li = threadIdx.y;      // 0..7
#pragma unroll
    for (int r = 0; r < 4; ++r) {
        int i = li + (r << 3);
        tile[i][lt] = x[((size_t)b * I_ + (i0 + i)) * T_ + (t0 + lt)];
    }
    __syncthreads();
#pragma unroll
    for (int r = 0; r < 4; ++r) {
        int tt = li + (r << 3);
        xT[((size_t)(t0 + tt) * B_ + b) * I_ + (i0 + lt)] = tile[lt][tt];
    }
}

__global__ __launch_bounds__(512, 1)
void lstm_fused(const float* __restrict__ x,
                const float* __restrict__ xT,     // nullptr -> strided fallback
                const float* __restrict__ Wih,
                const float* __restrict__ Whh,
                const float* __restrict__ bih,
                const float* __restrict__ bhh,
                const float* __restrict__ h0,
                const float* __restrict__ c0,
                float* __restrict__ out,
                float* __restrict__ hbuf,
                unsigned* __restrict__ cnt)
{
    // smem arena: redA[16][133] f32x4 (34048 B, aliased by red2[4][133])
    // | act[8][772] f32 (24704 B) | hsh[128] f32 (512 B)
    __shared__ char smem[59264];
    f32x4* redA = (f32x4*)smem;
    f32x4* red2 = (f32x4*)smem;                       // alias (sync-protected)
    float* act  = (float*)(smem + 34048);
    float* hsh  = (float*)(smem + 34048 + 24704);

    const int tid  = threadIdx.x;
    const int wv   = tid >> 6;
    const int lane = tid & 63;
    const int jl   = lane & 15;           // j within block's 16 / lane-in-slice-group
    const int sl   = wv * 4 + (lane >> 4);// k-slice 0..31 == producer index for h-part

    // fixed team assignment: 8 teams (b-tiles) x 32 j-blocks
    const int blk = blockIdx.x;
    const int bt  = blk >> 5;
    const int jt  = blk & 31;
    const int b0  = bt << 3;
    const int j0  = jt << 4;
    unsigned* flags  = cnt + C_FLAG + bt * 512;   // team's flags, 64B stride per producer
    unsigned* myflag = flags + jt * 16;
    const unsigned* pflag = flags + sl * 16;      // this thread's producer flag

    // ---- one-time: weight slices into registers ----
    // x-part: k in [sl*8, sl*8+8)  |  h-part: k-256 in [sl*16, sl*16+16)
    const int j = j0 + jl;
    float w_x[4][8];
    float w_h[4][16];
#pragma unroll
    for (int g = 0; g < 4; ++g) {
        const size_t row = (size_t)(g * H_ + j);
#pragma unroll
        for (int kk = 0; kk < 8; ++kk)  w_x[g][kk] = Wih[row * I_ + (sl << 3) + kk];
#pragma unroll
        for (int kk = 0; kk < 16; ++kk) w_h[g][kk] = Whh[row * H_ + (sl << 4) + kk];
    }

    // finalizer (tid<128) per-(b,j) state
    const int fb = b0 + (tid >> 4);
    const int fj = j0 + (tid & 15);
    float c = 0.f;
    f32x4 bias4 = {0.f, 0.f, 0.f, 0.f};
    if (tid < 128) {
        c = c0[(size_t)fb * H_ + fj];
#pragma unroll
        for (int g = 0; g < 4; ++g) bias4[g] = bih[g * H_ + fj] + bhh[g * H_ + fj];
    }

    float* enc = out + BH_;
    const int pr = tid & 127;    // reduce pair (bq = pr>>4, jl = pr&15)
    const int qq = tid >> 7;     // reduce quarter 0..3

    // h-stage role within slice-group: bq = jl>>1, 8-float half = jl&1
    const int hs_bq  = jl >> 1;
    const int hs_off = (sl << 4) + ((jl & 1) << 3);   // k-offset within h row

    // prologue: prefetch x slab for t=0
    float4 xv;
    if (xT) xv = ((const float4*)(xT + (size_t)b0 * I_))[tid];

    for (int t = 0; t < T_; ++t) {
        // ---- (a) commit x(t) to act[.][0..256) ----
        if (xT) {
            *(float4*)(act + (tid >> 6) * 772 + ((tid & 63) << 2)) = xv;
        } else {
#pragma unroll
            for (int r = 0; r < 4; ++r) {
                int flat = tid + (r << 9), bb = flat >> 8, ii = flat & 255;
                act[bb * 772 + ii] = x[((size_t)(b0 + bb) * I_ + ii) * T_ + t];
            }
        }
        __syncthreads();                                   // act_x ready; prev-step act reads done

        // ---- (b) FMA x-part (independent of h(t-1)) ----
        f32x4 r4[8];
#pragma unroll
        for (int bq = 0; bq < 8; ++bq) {
            const f32x4* ap = (const f32x4*)(act + bq * 772 + (sl << 3));
            float s0 = 0.f, s1 = 0.f, s2 = 0.f, s3 = 0.f;
#pragma unroll
            for (int q2 = 0; q2 < 2; ++q2) {
                f32x4 a = ap[q2];
#pragma unroll
                for (int e = 0; e < 4; ++e) {
                    const float av = a[e];
                    const int kk = q2 * 4 + e;
                    s0 += av * w_x[0][kk]; s1 += av * w_x[1][kk];
                    s2 += av * w_x[2][kk]; s3 += av * w_x[3][kk];
                }
            }
            r4[bq] = (f32x4){s0, s1, s2, s3};
        }

        // ---- (c) prefetch x(t+1) into registers (hides under the wait) ----
        if (xT && t + 1 < T_)
            xv = ((const float4*)(xT + (size_t)(t + 1) * B_ * I_ + (size_t)b0 * I_))[tid];

        // ---- (d) PER-WAVE wait: only this wave's 4 producers (bounded) ----
        if (t > 0) {
            const unsigned tgt = (unsigned)t;
            for (unsigned it = 0; it < (1u << 17); ++it) {
                unsigned v = flag_load(pflag);
                if (__all((int)(v >= tgt))) break;         // wave's 4 flags all ready
                __builtin_amdgcn_s_sleep(1);
            }
        }

        // ---- (e) slice-group stages its own producer's slice (same-wave LDS) ----
        {
            const float* hsrc = t ? (hbuf + (size_t)((t - 1) & 1) * BH_) : h0;
            const float* src = hsrc + (size_t)(b0 + hs_bq) * H_ + hs_off;
            f32x4 v0, v1;
            asm volatile("global_load_dwordx4 %0, %2, off sc0 sc1\n\t"
                         "global_load_dwordx4 %1, %3, off sc0 sc1\n\t"
                         "s_waitcnt vmcnt(0)"
                         : "=&v"(v0), "=&v"(v1) : "v"(src), "v"(src + 4) : "memory");
            float* dst = act + hs_bq * 772 + 256 + hs_off;
            *(f32x4*)dst = v0;
            *(f32x4*)(dst + 4) = v1;
            asm volatile("s_waitcnt lgkmcnt(0)" ::: "memory");  // wave-local visibility
            __builtin_amdgcn_sched_barrier(0);
        }

        // ---- (f) FMA h-part (reads only this group's 16-k window) ----
#pragma unroll
        for (int bq = 0; bq < 8; ++bq) {
            const f32x4* ap = (const f32x4*)(act + bq * 772 + 256 + (sl << 4));
            float s0 = 0.f, s1 = 0.f, s2 = 0.f, s3 = 0.f;
#pragma unroll
            for (int q4 = 0; q4 < 4; ++q4) {
                f32x4 a = ap[q4];
#pragma unroll
                for (int e = 0; e < 4; ++e) {
                    const float av = a[e];
                    const int kk = q4 * 4 + e;
                    s0 += av * w_h[0][kk]; s1 += av * w_h[1][kk];
                    s2 += av * w_h[2][kk]; s3 += av * w_h[3][kk];
                }
            }
            r4[bq] += (f32x4){s0, s1, s2, s3};
        }

        // ---- (g) hierarchical reduce over 32 k-slices ----
        if (wv < 4) {
#pragma unroll
            for (int bq = 0; bq < 8; ++bq) redA[sl * 133 + bq * 16 + jl] = r4[bq];
        }
        __syncthreads();
        f32x4 acc = redA[(qq * 4 + 0) * 133 + pr] + redA[(qq * 4 + 1) * 133 + pr]
                  + redA[(qq * 4 + 2) * 133 + pr] + redA[(qq * 4 + 3) * 133 + pr];
        __syncthreads();
        if (wv >= 4) {
#pragma unroll
            for (int bq = 0; bq < 8; ++bq) redA[(sl - 16) * 133 + bq * 16 + jl] = r4[bq];
        }
        __syncthreads();
        acc += redA[(qq * 4 + 0) * 133 + pr] + redA[(qq * 4 + 1) * 133 + pr]
             + redA[(qq * 4 + 2) * 133 + pr] + redA[(qq * 4 + 3) * 133 + pr];
        __syncthreads();                       // protect redA reads before alias write
        red2[qq * 133 + pr] = acc;
        __syncthreads();

        // ---- (h) finalize: gates, state, enc ----
        if (tid < 128) {
            f32x4 G = red2[0 * 133 + tid] + red2[1 * 133 + tid]
                    + red2[2 * 133 + tid] + red2[3 * 133 + tid] + bias4;
            float ig = sigm(G[0]), fg = sigm(G[1]), gg = tanhf(G[2]), og = sigm(G[3]);
            c = fg * c + ig * gg;
            float hv = og * tanhf(c);
            hsh[tid] = hv;
            enc[((size_t)fb * H_ + fj) * T_ + t] = hv;          // plain cached store
            if (t == T_ - 1) out[(size_t)fb * H_ + fj] = hv;
        }

        // ---- (i) publish h (8 full 64B lines, sc0 sc1), drain, flag ----
        if (t != T_ - 1) {
            __syncthreads();                   // hsh ready
            if (tid < 32) {
                int bq = tid >> 2, q4 = tid & 3;
                f32x4 v = *(const f32x4*)(hsh + bq * 16 + q4 * 4);
                float* dst = hbuf + (size_t)(t & 1) * BH_
                           + (size_t)(b0 + bq) * H_ + j0 + q4 * 4;
                asm volatile("global_store_dwordx4 %0, %1, off sc0 sc1"
                             :: "v"(dst), "v"(v) : "memory");
            }
            if (wv == 0) {
                asm volatile("s_waitcnt vmcnt(0)" ::: "memory"); // wave0 publish at IF
                if (tid == 0) flag_store(myflag, (unsigned)(t + 1));
            }
        }
    }
}

extern "C" void kernel_launch(void* const* d_in, const int* in_sizes, int n_in,
                              void* d_out, int out_size, void* d_ws, size_t ws_size,
                              hipStream_t stream)
{
    (void)in_sizes; (void)n_in; (void)out_size;
    const float* x   = (const float*)d_in[0];
    const float* Wih = (const float*)d_in[1];
    const float* Whh = (const float*)d_in[2];
    const float* bih = (const float*)d_in[3];
    const float* bhh = (const float*)d_in[4];
    const float* h0  = (const float*)d_in[5];
    const float* c0  = (const float*)d_in[6];
    float* out  = (float*)d_out;
    float* hbuf = (float*)d_ws;
    unsigned* cnt = (unsigned*)((char*)d_ws + WS_CNT_OFF);

    const size_t xt_bytes = (size_t)T_ * B_ * I_ * sizeof(float);
    float* xT = nullptr;
    if (ws_size >= WS_XT_OFF + xt_bytes)
        xT = (float*)((char*)d_ws + WS_XT_OFF);

    // zero flags every launch (graph-replay deterministic)
    hipMemsetAsync((char*)d_ws + WS_CNT_OFF, 0, 65536, stream);
    if (xT)
        transpose_x<<<dim3(T_ / 32, I_ / 32, B_), dim3(32, 8), 0, stream>>>(x, xT);

    void* args[] = { (void*)&x, (void*)&xT, (void*)&Wih, (void*)&Whh, (void*)&bih,
                     (void*)&bhh, (void*)&h0, (void*)&c0, (void*)&out,
                     (void*)&hbuf, (void*)&cnt };
    hipLaunchCooperativeKernel((void*)lstm_fused, dim3(256), dim3(512), args, 0, stream);
}